// Round 9
// baseline (411.144 us; speedup 1.0000x reference)
//
#include <hip/hip_runtime.h>
#include <math.h>
#include <limits.h>

#define BSZ 16
#define NQ  900
#define NCL 92
#define NT  256
#define SUMT (BSZ*NT)   /* 4096 */
#define MM  NQ          /* JV columns (queries) */
#define NN  NT          /* JV rows (targets)    */
#define NSLOT 15        /* ceil(900/64) columns per lane */
#define QCHUNK 60       /* q's per cost block: 900 = 15*60 */
#define WAVES 16        /* bidding waves in lsa_kernel */
#define BLKT (WAVES*64) /* 1024 threads */
#define BIDS (2*WAVES)  /* bids per round (2 rows per wave) */
#define RING 512        /* free-row ring buffer (live <= ~255) */
#define ARR_CAP 4000    /* global bid cap; Phase B finishes exactly */

// ---------------------------------------------------------------------------
// Kernel B: cost matrix with IN-BLOCK softmax (fused prob), coalesced C
// stores; LDS staging of 60 logit rows + 60 query boxes. Per-row softmax
// uses the exact shuffle-reduction pattern of the old prob_kernel (same op
// order -> bit-identical P -> bit-identical C). Diag blocks (blockIdx.x==b)
// also write costT[b][t][q] (thread owns t=tid; 60 contiguous floats) and
// accumulate the packed row-min (ordered-f32-key<<32 | q) -> atomicMin into
// upack[b*NN+t] (same packing/tie semantics as always: lowest q wins).
// upack must be pre-set to 0xFF...F.
// ---------------------------------------------------------------------------
__global__ __launch_bounds__(256) void cost_kernel2(
    const float* __restrict__ logits, const float* __restrict__ boxes,
    const int* __restrict__ labels, const float* __restrict__ tbox,
    float* __restrict__ C, float* __restrict__ costT,
    unsigned long long* __restrict__ upack) {
#pragma clang fp contract(off)
  const int tid = threadIdx.x;
  const int jt = blockIdx.x * 256 + tid;
  const int b  = blockIdx.z;
  const int q0 = blockIdx.y * QCHUNK;
  const bool diag = (blockIdx.x == b) && (costT != nullptr);

  __shared__ float sP[QCHUNK * NCL];   // 5520 floats: logits -> probs
  __shared__ float sB[QCHUNK * 4];     // 240 floats

  const size_t pbase = (size_t)(b * NQ + q0) * NCL;
  for (int x = tid; x < QCHUNK * NCL; x += 256) sP[x] = logits[pbase + x];
  const size_t bbase = (size_t)(b * NQ + q0) * 4;
  if (tid < QCHUNK * 4) sB[tid] = boxes[bbase + tid];
  __syncthreads();

  // in-block softmax: 4 waves x 15 rows, prob_kernel's exact pattern
  {
    const int w = tid >> 6, lane = tid & 63;
    for (int r = w; r < QCHUNK; r += 4) {
      const float x1 = sP[r * NCL + lane];
      const float x2 = (lane + 64 < NCL) ? sP[r * NCL + lane + 64] : -INFINITY;
      float m = fmaxf(x1, x2);
      #pragma unroll
      for (int k = 1; k < 64; k <<= 1) m = fmaxf(m, __shfl_xor(m, k));
      const float e1 = expf(x1 - m);
      const float e2 = (lane + 64 < NCL) ? expf(x2 - m) : 0.f;
      float ssum = e1 + e2;
      #pragma unroll
      for (int k = 1; k < 64; k <<= 1) ssum += __shfl_xor(ssum, k);
      sP[r * NCL + lane] = e1 / ssum;
      if (lane + 64 < NCL) sP[r * NCL + lane + 64] = e2 / ssum;
    }
  }
  __syncthreads();

  const float4 tb = ((const float4*)tbox)[jt];
  const int lab = labels[jt];
  const float tx1 = tb.x - 0.5f*tb.z, ty1 = tb.y - 0.5f*tb.w;
  const float tx2 = tb.x + 0.5f*tb.z, ty2 = tb.y + 0.5f*tb.w;
  const float area2 = (tx2 - tx1) * (ty2 - ty1);

  float* tr = diag ? (costT + ((size_t)(b * NT + tid)) * MM + q0) : nullptr;
  unsigned long long best = ~0ull;

  for (int qq = 0; qq < QCHUNK; ++qq) {
    const float cx = sB[qq*4+0], cy = sB[qq*4+1];
    const float w  = sB[qq*4+2], h  = sB[qq*4+3];
    const float cc = -sP[qq*NCL + lab];
    const float bx1 = cx - 0.5f*w, by1 = cy - 0.5f*h;
    const float bx2 = cx + 0.5f*w, by2 = cy + 0.5f*h;
    const float area1 = (bx2 - bx1) * (by2 - by1);
    const float d0 = fabsf(cx - tb.x), d1 = fabsf(cy - tb.y);
    const float d2 = fabsf(w - tb.z),  d3 = fabsf(h - tb.w);
    const float cb = ((d0 + d1) + d2) + d3;
    const float ltx = fmaxf(bx1, tx1), lty = fmaxf(by1, ty1);
    const float rbx = fminf(bx2, tx2), rby = fminf(by2, ty2);
    const float iw = fmaxf(rbx - ltx, 0.f), ih = fmaxf(rby - lty, 0.f);
    const float inter = iw * ih;
    const float uni = (area1 + area2) - inter;
    const float iou = inter / uni;
    const float ex1 = fminf(bx1, tx1), ey1 = fminf(by1, ty1);
    const float ex2 = fmaxf(bx2, tx2), ey2 = fmaxf(by2, ty2);
    const float ew = fmaxf(ex2 - ex1, 0.f), eh = fmaxf(ey2 - ey1, 0.f);
    const float ea = ew * eh;
    const float giou = iou - (ea - uni) / ea;
    const float cval = (5.0f*cb + 1.0f*cc) + 2.0f*(-giou);
    C[(size_t)(b*NQ + q0 + qq) * SUMT + jt] = cval;
    if (diag) {
      tr[qq] = cval;
      unsigned bts = __float_as_uint(cval);
      bts = (bts & 0x80000000u) ? ~bts : (bts | 0x80000000u);
      const unsigned long long pk =
          ((unsigned long long)bts << 32) | (unsigned)(q0 + qq);
      if (pk < best) best = pk;
    }
  }
  if (diag && upack) atomicMin(&upack[b * NN + tid], best);
}

// ---------------------------------------------------------------------------
// Kernel D: JV LSA, 1024 threads/block, one block per image.
// Phase A: u[i]=row-min (decoded from upack, or in-kernel scan) + greedy
//   claims via LDS atomicMin (lowest row wins == sequential greedy).
// Phase A2: 32-bid Jacobi augmenting-row-reduction (2 rows per wave/round).
//   All bids in a round are priced at round-start vs; commits in queue order
//   to DISTINCT columns (same-column conflicts requeue). Soundness:
//   committed pair has reduced cost exactly 0 (CS); stale b2 <= true second
//   min, so u[i]=b2 keeps c-u-v >= 0 everywhere (feasibility); v only
//   decreases; columns never unassign, so free columns keep v=0 (rectangular
//   sink condition). Hard cap ARR_CAP; Phase B finishes exactly regardless.
// Phase B (wave 0): Dijkstra for remaining unassigned rows, lazy deltas.
// ---------------------------------------------------------------------------
__global__ __launch_bounds__(BLKT) void lsa_kernel(
    const float* __restrict__ C, const float* __restrict__ costT,
    const unsigned long long* __restrict__ upack,
    float* __restrict__ rows_out, float* __restrict__ cols_out) {
  const int b   = blockIdx.x;
  const int tid = threadIdx.x;

  __shared__ double u[NN + 1];
  __shared__ int    p[MM + 1];
  __shared__ int    wayl[MM + 1];
  __shared__ int    claim[MM + 1];
  __shared__ int    rowargmin[NN];
  __shared__ unsigned char rowass[NN];
  __shared__ int    listj[MM + 1];
  __shared__ double listD[MM + 1];
  __shared__ double vs[MM + 1];
  __shared__ int    qring[RING];
  __shared__ int    qhead_sh, qtail_sh, steps_sh;
  __shared__ int    bid_i[BIDS], bid_j[BIDS];
  __shared__ double bid_b1[BIDS], bid_b2[BIDS];

  // ---- Phase A: row minima + greedy claims (LDS) ----
  for (int j = tid; j <= MM; j += BLKT) { p[j] = 0; claim[j] = INT_MAX; vs[j] = 0.0; }
  if (upack) {
    if (tid < NN) {
      const unsigned long long pk = upack[b * NN + tid];
      const unsigned key = (unsigned)(pk >> 32);
      const unsigned bts = (key & 0x80000000u) ? (key & 0x7fffffffu) : ~key;
      u[tid + 1] = (double)__uint_as_float(bts);
      rowargmin[tid] = (int)(pk & 0xffffffffu);
    }
  } else {
    if (tid < NN) {
      const float* rowptr = C + ((size_t)(b * NQ)) * SUMT + b * NT + tid;
      float mn = INFINITY; int am = 0;
      #pragma unroll 4
      for (int q = 0; q < NQ; ++q) {
        const float cv = rowptr[(size_t)q * SUMT];
        if (cv < mn) { mn = cv; am = q; }
      }
      u[tid + 1] = (double)mn;   // exact: pure f32 min, no arithmetic
      rowargmin[tid] = am;
    }
  }
  if (tid == 0) u[0] = 0.0;
  __syncthreads();
  if (tid < NN) atomicMin(&claim[rowargmin[tid] + 1], tid + 1);
  __syncthreads();
  if (tid < NN) {
    const int am = rowargmin[tid];
    const bool got = (claim[am + 1] == tid + 1);
    rowass[tid] = got ? 1 : 0;
    if (got) p[am + 1] = tid + 1;
  }
  __syncthreads();

  const int lane = tid & 63;
  const int wv   = tid >> 6;
  const float* slab = costT ? costT + (size_t)b * NT * MM : nullptr;

  // ---- build free-row queue (wave 0, ascending row index) ----
  if (tid < 64) {
    int fcnt = 0;
    #pragma unroll
    for (int c = 0; c < 4; ++c) {
      const bool fr = !rowass[c * 64 + tid];
      const unsigned long long mk = __ballot(fr);
      const int rk = __popcll(mk & ((1ull << tid) - 1ull));
      if (fr) qring[fcnt + rk] = c * 64 + tid + 1;
      fcnt += __popcll(mk);
    }
    if (tid == 0) { qhead_sh = 0; qtail_sh = fcnt; steps_sh = 0; }
  }
  __syncthreads();

  // ---- Phase A2: 32-bid Jacobi ARR (all waves, 2 rows/wave/round) ----
  if (slab) {
    while (true) {
      const int head = qhead_sh, tail = qtail_sh, st = steps_sh;
      if (head >= tail || st >= ARR_CAP) break;
      int navail = tail - head; if (navail > BIDS) navail = BIDS;

      #pragma unroll
      for (int rep = 0; rep < 2; ++rep) {
        const int slot = rep * WAVES + wv;
        if (slot < navail) {
          const int i = qring[(head + slot) & (RING - 1)];
          const float* rowp = slab + (size_t)(i - 1) * MM;
          double b1 = INFINITY, b2 = INFINITY; int j1 = MM + 2;
          #pragma unroll
          for (int s = 0; s < NSLOT; ++s) {
            const int j = s * 64 + lane + 1;
            if (j <= MM) {
              const double cand = (double)rowp[j - 1] - vs[j];
              if (cand < b1) { b2 = b1; b1 = cand; j1 = j; }
              else           { b2 = fmin(b2, cand); }
            }
          }
          #pragma unroll
          for (int m = 1; m < 64; m <<= 1) {
            const double ob1 = __shfl_xor(b1, m);
            const double ob2 = __shfl_xor(b2, m);
            const int    oj1 = __shfl_xor(j1, m);
            if (ob1 < b1 || (ob1 == b1 && oj1 < j1)) {
              b2 = fmin(b1, ob2); b1 = ob1; j1 = oj1;
            } else {
              b2 = fmin(b2, ob1);
            }
          }
          if (lane == 0) { bid_i[slot] = i; bid_j[slot] = j1; bid_b1[slot] = b1; bid_b2[slot] = b2; }
        }
      }
      __syncthreads();

      if (tid < navail) {          // parallel commit, one thread per bid
        const int j1 = bid_j[tid];
        bool dup = false;
        for (int e = 0; e < tid; ++e) if (bid_j[e] == j1) dup = true;
        if (dup) {
          const int slot = atomicAdd(&qtail_sh, 1);
          qring[slot & (RING - 1)] = bid_i[tid];       // requeue, rebid next round
        } else {
          const double amt = bid_b2[tid] - bid_b1[tid]; // >= 0
          vs[j1] -= amt;
          u[bid_i[tid]] = bid_b2[tid];
          const int k = p[j1];
          p[j1] = bid_i[tid];
          rowass[bid_i[tid] - 1] = 1;
          if (k) {
            rowass[k - 1] = 0;
            const int slot = atomicAdd(&qtail_sh, 1);
            qring[slot & (RING - 1)] = k;              // displaced row
          }
        }
      }
      if (tid == 0) { qhead_sh += navail; steps_sh += navail; }
      __syncthreads();
    }
  }

  if (tid >= 64) return;           // Phase B + emit: wave 0 only

  double v_r[NSLOT];
  #pragma unroll
  for (int s = 0; s < NSLOT; ++s) {
    const int j = s * 64 + lane + 1;
    v_r[s] = (j <= MM) ? vs[j] : 0.0;
  }

  // ---- Phase B: Dijkstra for any remaining unassigned rows (wave 0) ----
  for (int ii = 1; ii <= NN; ++ii) {
    if (rowass[ii - 1]) continue;

    double M_r[NSLOT];
    #pragma unroll
    for (int s = 0; s < NSLOT; ++s) M_r[s] = INFINITY;
    unsigned int used = (lane < 4) ? 0u : (1u << 14);  // kill slot-14 tail
    int    lcount = 0;
    int    j0 = 0;
    double Dsel = 0.0;          // D at j0's selection (0 for virtual col)
    double D = 0.0;
    bool   okrow = true;

    while (true) {
      const int    i0 = (j0 == 0) ? ii : p[j0];
      const double us = u[i0] - Dsel;
      const float* rowp = slab ? slab + (size_t)(i0 - 1) * MM : nullptr;

      double best = INFINITY; int bestj = MM + 2;
      #pragma unroll
      for (int s = 0; s < NSLOT; ++s) {
        if (!(used & (1u << s))) {
          const int j = s * 64 + lane + 1;
          const float cf = rowp ? rowp[j - 1]
              : C[((size_t)(b*NQ + (j-1)))*SUMT + (b*NT + i0 - 1)];
          const double cand = ((double)cf - v_r[s]) - us;
          if (cand < M_r[s]) { M_r[s] = cand; wayl[j] = j0; }
          if (M_r[s] < best) { best = M_r[s]; bestj = j; }
        }
      }
      #pragma unroll
      for (int m = 1; m < 64; m <<= 1) {
        const double ov = __shfl_xor(best, m);
        const int    oj = __shfl_xor(bestj, m);
        if (ov < best || (ov == best && oj < bestj)) { best = ov; bestj = oj; }
      }
      const int j1 = bestj;
      if (j1 > MM) { okrow = false; break; }     // safety: no candidate
      D = best;                                  // accumulated delta = M[j1]
      if (lane == ((j1 - 1) & 63)) used |= 1u << ((j1 - 1) >> 6);
      if (p[j1] == 0) { j0 = j1; break; }        // free column: done
      if (lane == 0) { listj[lcount] = j1; listD[lcount] = D; }
      lcount++;
      j0 = j1; Dsel = D;
    }

    if (okrow) {
      // batched dual updates (old p), then augmentation
      for (int e = 0; e < lcount; ++e) {
        const int    je = listj[e];
        const double amt = D - listD[e];
        if (lane == ((je - 1) & 63)) v_r[(je - 1) >> 6] -= amt;
        if (lane == 0) u[p[je]] += amt;
      }
      if (lane == 0) {
        u[ii] += D;                              // virtual column j0=0
        int jj = j0;
        while (jj) { const int jn = wayl[jj]; const int pn = (jn == 0) ? ii : p[jn]; p[jj] = pn; jj = jn; }
        rowass[ii - 1] = 1;
      }
    }
  }

  // ---- emit (query, target) pairs in ascending query order ----
  int base = 0;
  #pragma unroll
  for (int s = 0; s < NSLOT; ++s) {
    const int j = s * 64 + lane + 1;
    const bool a = (j <= MM) && (p[j] > 0);
    const unsigned long long mask = __ballot(a);
    const int rank = __popcll(mask & ((1ull << lane) - 1ull));
    if (a) {
      rows_out[b*NT + base + rank] = (float)(j - 1);
      cols_out[b*NT + base + rank] = (float)(p[j] - 1);
    }
    base += __popcll(mask);
  }
}

extern "C" void kernel_launch(void* const* d_in, const int* in_sizes, int n_in,
                              void* d_out, int out_size, void* d_ws, size_t ws_size,
                              hipStream_t stream) {
  const float* logits = (const float*)d_in[0];
  const float* boxes  = (const float*)d_in[1];
  const int*   labels = (const int*)d_in[2];
  const float* tbox   = (const float*)d_in[3];

  float* C    = (float*)d_out;
  float* rows = C + (size_t)BSZ * NQ * SUMT;
  float* cols = rows + (size_t)BSZ * NT;

  const size_t needT = (size_t)SUMT * MM * sizeof(float);        // ~14.7 MB
  const size_t needU = (size_t)BSZ * NN * sizeof(unsigned long long);

  if (ws_size >= needT + needU) {
    float* costT = (float*)d_ws;
    unsigned long long* upack = (unsigned long long*)(costT + (size_t)SUMT * MM);
    hipMemsetAsync(upack, 0xFF, needU, stream);
    hipLaunchKernelGGL(cost_kernel2, dim3(SUMT/256, NQ/QCHUNK, BSZ), dim3(256), 0, stream,
                       logits, boxes, labels, tbox, C, costT, upack);
    hipLaunchKernelGGL(lsa_kernel, dim3(BSZ), dim3(BLKT), 0, stream,
                       C, costT, upack, rows, cols);
  } else if (ws_size >= needT) {
    float* costT = (float*)d_ws;
    hipLaunchKernelGGL(cost_kernel2, dim3(SUMT/256, NQ/QCHUNK, BSZ), dim3(256), 0, stream,
                       logits, boxes, labels, tbox, C, costT, (unsigned long long*)nullptr);
    hipLaunchKernelGGL(lsa_kernel, dim3(BSZ), dim3(BLKT), 0, stream,
                       C, costT, (const unsigned long long*)nullptr, rows, cols);
  } else {
    hipLaunchKernelGGL(cost_kernel2, dim3(SUMT/256, NQ/QCHUNK, BSZ), dim3(256), 0, stream,
                       logits, boxes, labels, tbox, C, (float*)nullptr,
                       (unsigned long long*)nullptr);
    hipLaunchKernelGGL(lsa_kernel, dim3(BSZ), dim3(BLKT), 0, stream,
                       C, (float*)nullptr, (const unsigned long long*)nullptr, rows, cols);
  }
}